// Round 1
// baseline (242.306 us; speedup 1.0000x reference)
//
#include <hip/hip_runtime.h>
#include <hip/hip_bf16.h>

typedef __attribute__((ext_vector_type(8))) short short8;
typedef __attribute__((ext_vector_type(4))) short short4v;
typedef __attribute__((ext_vector_type(4))) float f32x4;

namespace {
constexpr int NSEQ = 2048;
constexpr int NHEAD = 16;
constexpr int NDIM = 128;
constexpr int BQ = 128;   // q rows per block
constexpr int WQ = 32;    // q rows per wave
constexpr int BKV = 32;   // kv tile
constexpr int NWAVE = 4;
constexpr int VTS = 40;   // vt_lds row stride (shorts) — 2-way banks
constexpr int PS = 40;    // p_lds row stride (shorts)
}

// int (value in [-128,127]) -> bf16 bits, exact (<=8 significant bits)
__device__ __forceinline__ short i2bf(int v) {
    union { float f; unsigned u; } x;
    x.f = (float)v;
    return (short)(x.u >> 16);
}

// float -> bf16 bits, RNE
__device__ __forceinline__ short f2bf(float f) {
    union { float f; unsigned u; } x;
    x.f = f;
    unsigned u = x.u;
    u = (u + 0x7fffu + ((u >> 16) & 1u)) >> 16;
    return (short)u;
}

__global__ __launch_bounds__(256, 2)
void qattn_fwd(const int* __restrict__ qq, const int* __restrict__ kq,
               const int* __restrict__ vq, const float* __restrict__ qsc,
               const float* __restrict__ ksc, const float* __restrict__ vsc,
               float* __restrict__ out)
{
    const int qi = (int)gridDim.x - 1 - (int)blockIdx.x;  // heavy blocks first
    const int q0 = qi * BQ;
    const int bh = blockIdx.y;
    const int b = bh >> 4;
    const int h = bh & 15;
    const int t = threadIdx.x;
    const int lane = t & 63;
    const int w = t >> 6;
    const int g = lane >> 4;
    const int fr = lane & 15;

    __shared__ __align__(16) short k_lds[BKV * NDIM];        // XOR-swizzled rows
    __shared__ __align__(16) short vt_lds[NDIM * VTS];       // V transposed [d][kv]
    __shared__ __align__(16) short p_lds[NWAVE][WQ * PS];    // per-wave P tile

    const float sc = qsc[h] * ksc[h] * 0.08838834764831845f; // qs*ks/sqrt(128)
    const float vscale = vsc[h];

    // ---- load Q fragments (exact int->bf16) ----
    short8 qf[2][4];
    #pragma unroll
    for (int m = 0; m < 2; ++m) {
        const int qrow = q0 + w * WQ + m * 16 + fr;
        const int* qp = qq + ((b * NSEQ + qrow) * NHEAD + h) * NDIM;
        #pragma unroll
        for (int c = 0; c < 4; ++c) {
            const int d = c * 32 + g * 8;
            int4 a0 = *(const int4*)(qp + d);
            int4 a1 = *(const int4*)(qp + d + 4);
            short8 f;
            f[0] = i2bf(a0.x); f[1] = i2bf(a0.y); f[2] = i2bf(a0.z); f[3] = i2bf(a0.w);
            f[4] = i2bf(a1.x); f[5] = i2bf(a1.y); f[6] = i2bf(a1.z); f[7] = i2bf(a1.w);
            qf[m][c] = f;
        }
    }

    const f32x4 fzero = {0.f, 0.f, 0.f, 0.f};
    f32x4 o_acc[2][8];
    float m_run[2][4], l_run[2][4];
    #pragma unroll
    for (int m = 0; m < 2; ++m) {
        #pragma unroll
        for (int dt = 0; dt < 8; ++dt) o_acc[m][dt] = fzero;
        #pragma unroll
        for (int r = 0; r < 4; ++r) { m_run[m][r] = -3e38f; l_run[m][r] = 0.f; }
    }

    const int q_hi = q0 + w * WQ + WQ - 1;
    const int kv_end = q0 + BQ;

    for (int kv = 0; kv < kv_end; kv += BKV) {
        __syncthreads();   // previous iteration's LDS reads done
        // ---- stage K tile [32][128] int32 -> bf16, XOR-swizzled ----
        {
            const int krow = t >> 3;
            const int d0 = (t & 7) * 16;
            const int* kp = kq + ((b * NSEQ + kv + krow) * NHEAD + h) * NDIM + d0;
            int4 a0 = *(const int4*)(kp + 0);
            int4 a1 = *(const int4*)(kp + 4);
            int4 a2 = *(const int4*)(kp + 8);
            int4 a3 = *(const int4*)(kp + 12);
            short8 lo, hi;
            lo[0]=i2bf(a0.x); lo[1]=i2bf(a0.y); lo[2]=i2bf(a0.z); lo[3]=i2bf(a0.w);
            lo[4]=i2bf(a1.x); lo[5]=i2bf(a1.y); lo[6]=i2bf(a1.z); lo[7]=i2bf(a1.w);
            hi[0]=i2bf(a2.x); hi[1]=i2bf(a2.y); hi[2]=i2bf(a2.z); hi[3]=i2bf(a2.w);
            hi[4]=i2bf(a3.x); hi[5]=i2bf(a3.y); hi[6]=i2bf(a3.z); hi[7]=i2bf(a3.w);
            const int sw = (krow & 7) << 3;
            *(short8*)&k_lds[(krow * NDIM + d0) ^ sw] = lo;
            *(short8*)&k_lds[(krow * NDIM + d0 + 8) ^ sw] = hi;
        }
        // ---- stage V tile transposed: vt_lds[d][kv], 4x4 register transpose ----
        {
            const int kvg = t >> 5;   // 0..7 -> kv rows kvg*4..+3
            const int dg = t & 31;    // 0..31 -> d cols dg*4..+3
            const int* vp = vq + ((b * NSEQ + kv + kvg * 4) * NHEAD + h) * NDIM + dg * 4;
            int4 a0 = *(const int4*)(vp + 0 * NHEAD * NDIM);
            int4 a1 = *(const int4*)(vp + 1 * NHEAD * NDIM);
            int4 a2 = *(const int4*)(vp + 2 * NHEAD * NDIM);
            int4 a3 = *(const int4*)(vp + 3 * NHEAD * NDIM);
            short4v c0 = { i2bf(a0.x), i2bf(a1.x), i2bf(a2.x), i2bf(a3.x) };
            short4v c1 = { i2bf(a0.y), i2bf(a1.y), i2bf(a2.y), i2bf(a3.y) };
            short4v c2 = { i2bf(a0.z), i2bf(a1.z), i2bf(a2.z), i2bf(a3.z) };
            short4v c3 = { i2bf(a0.w), i2bf(a1.w), i2bf(a2.w), i2bf(a3.w) };
            short* vbase = &vt_lds[(dg * 4) * VTS + kvg * 4];
            *(short4v*)(vbase + 0 * VTS) = c0;
            *(short4v*)(vbase + 1 * VTS) = c1;
            *(short4v*)(vbase + 2 * VTS) = c2;
            *(short4v*)(vbase + 3 * VTS) = c3;
        }
        __syncthreads();   // staging visible

        if (kv > q_hi) continue;   // wave-uniform skip of fully-masked tiles

        // ---- QK^T: S[q 32][kv 32] per wave ----
        short8 kb[2][4];
        #pragma unroll
        for (int hf = 0; hf < 2; ++hf) {
            #pragma unroll
            for (int c = 0; c < 4; ++c) {
                const int row = hf * 16 + fr;
                const int d = c * 32 + g * 8;
                kb[hf][c] = *(const short8*)&k_lds[(row * NDIM + d) ^ ((row & 7) << 3)];
            }
        }

        #pragma unroll
        for (int m = 0; m < 2; ++m) {
            f32x4 s0 = fzero, s1 = fzero;
            #pragma unroll
            for (int c = 0; c < 4; ++c) {
                s0 = __builtin_amdgcn_mfma_f32_16x16x32_bf16(qf[m][c], kb[0][c], s0, 0, 0, 0);
                s1 = __builtin_amdgcn_mfma_f32_16x16x32_bf16(qf[m][c], kb[1][c], s1, 0, 0, 0);
            }
            // C/D layout: col = lane&15 (kv), row = (lane>>4)*4 + r (q)
            const int qbase = q0 + w * WQ + m * 16 + g * 4;
            float p0[4], p1[4], rmax[4], sf[4], psum[4];
            #pragma unroll
            for (int r = 0; r < 4; ++r) {
                const int qr = qbase + r;
                p0[r] = (kv + fr <= qr) ? s0[r] * sc : -3e38f;
                p1[r] = (kv + 16 + fr <= qr) ? s1[r] * sc : -3e38f;
                rmax[r] = fmaxf(p0[r], p1[r]);
            }
            #pragma unroll
            for (int off = 1; off < 16; off <<= 1) {
                #pragma unroll
                for (int r = 0; r < 4; ++r)
                    rmax[r] = fmaxf(rmax[r], __shfl_xor(rmax[r], off, 64));
            }
            #pragma unroll
            for (int r = 0; r < 4; ++r) {
                const float mn = fmaxf(m_run[m][r], rmax[r]);
                sf[r] = __expf(m_run[m][r] - mn);     // first tile: exp(0)=1 (m=-3e38 both)
                m_run[m][r] = mn;
                p0[r] = __expf(p0[r] - mn);           // masked: exp(-huge)=0
                p1[r] = __expf(p1[r] - mn);
                psum[r] = p0[r] + p1[r];
            }
            #pragma unroll
            for (int off = 1; off < 16; off <<= 1) {
                #pragma unroll
                for (int r = 0; r < 4; ++r)
                    psum[r] += __shfl_xor(psum[r], off, 64);
            }
            #pragma unroll
            for (int r = 0; r < 4; ++r)
                l_run[m][r] = l_run[m][r] * sf[r] + psum[r];
            #pragma unroll
            for (int dt = 0; dt < 8; ++dt) {
                #pragma unroll
                for (int r = 0; r < 4; ++r)
                    o_acc[m][dt][r] *= sf[r];
            }
            #pragma unroll
            for (int r = 0; r < 4; ++r) {
                const int qr = m * 16 + g * 4 + r;
                p_lds[w][qr * PS + fr]      = f2bf(p0[r]);
                p_lds[w][qr * PS + 16 + fr] = f2bf(p1[r]);
            }
        }

        // ---- PV: O[q 32][d 128] += P[q 32][kv 32] * V[kv 32][d 128] ----
        short8 pa0 = *(const short8*)&p_lds[w][(0 * 16 + fr) * PS + g * 8];
        short8 pa1 = *(const short8*)&p_lds[w][(1 * 16 + fr) * PS + g * 8];
        #pragma unroll
        for (int dt = 0; dt < 8; ++dt) {
            short8 vb = *(const short8*)&vt_lds[(dt * 16 + fr) * VTS + g * 8];
            o_acc[0][dt] = __builtin_amdgcn_mfma_f32_16x16x32_bf16(pa0, vb, o_acc[0][dt], 0, 0, 0);
            o_acc[1][dt] = __builtin_amdgcn_mfma_f32_16x16x32_bf16(pa1, vb, o_acc[1][dt], 0, 0, 0);
        }
    }

    // ---- epilogue: normalize, apply v_scale, store fp32 ----
    #pragma unroll
    for (int m = 0; m < 2; ++m) {
        #pragma unroll
        for (int r = 0; r < 4; ++r) {
            const int qrow = q0 + w * WQ + m * 16 + g * 4 + r;
            const float scale_r = vscale / l_run[m][r];
            float* op = out + ((b * NSEQ + qrow) * NHEAD + h) * NDIM;
            #pragma unroll
            for (int dt = 0; dt < 8; ++dt)
                op[dt * 16 + fr] = o_acc[m][dt][r] * scale_r;
        }
    }
}

extern "C" void kernel_launch(void* const* d_in, const int* in_sizes, int n_in,
                              void* d_out, int out_size, void* d_ws, size_t ws_size,
                              hipStream_t stream) {
    const int* qq = (const int*)d_in[0];
    const int* kq = (const int*)d_in[1];
    const int* vq = (const int*)d_in[2];
    const float* qsc = (const float*)d_in[3];
    const float* ksc = (const float*)d_in[4];
    const float* vsc = (const float*)d_in[5];
    float* out = (float*)d_out;
    (void)d_ws; (void)ws_size; (void)in_sizes; (void)n_in; (void)out_size;

    dim3 grid(NSEQ / BQ, 2 * NHEAD);  // 16 x 32 = 512 blocks
    qattn_fwd<<<grid, NWAVE * 64, 0, stream>>>(qq, kq, vq, qsc, ksc, vsc, out);
}

// Round 2
// 155.492 us; speedup vs baseline: 1.5583x; 1.5583x over previous
//
#include <hip/hip_runtime.h>
#include <hip/hip_bf16.h>

typedef __attribute__((ext_vector_type(8))) short short8;
typedef __attribute__((ext_vector_type(2))) short short2v;
typedef __attribute__((ext_vector_type(4))) float f32x4;

namespace {
constexpr int NSEQ = 2048;
constexpr int NHEAD = 16;
constexpr int NDIM = 128;
constexpr int BKV = 32;
constexpr int VTS = 40;   // vt_lds row stride (shorts)
constexpr int PS  = 40;   // p_lds row stride (shorts)
constexpr int ROWI = NHEAD * NDIM;   // 2048 ints per seq row
}

// int in [-128,127] -> bf16 bits, exact
__device__ __forceinline__ short i2bf(int v) {
    union { float f; unsigned u; } x; x.f = (float)v;
    return (short)(x.u >> 16);
}
// float -> bf16 bits, RNE
__device__ __forceinline__ short f2bf(float f) {
    union { float f; unsigned u; } x; x.f = f;
    unsigned u = (x.u + 0x7fffu + ((x.u >> 16) & 1u)) >> 16;
    return (short)u;
}

__global__ __launch_bounds__(512, 2)
void qattn_fwd(const int* __restrict__ qq, const int* __restrict__ kq,
               const int* __restrict__ vq, const float* __restrict__ qsc,
               const float* __restrict__ ksc, const float* __restrict__ vsc,
               float* __restrict__ out)
{
    // 1D grid 256: bh fastest -> same-bh pair-blocks land on the same XCD
    const int id = blockIdx.x;
    const int jj = id >> 5;            // pair index 0..7
    const int bh = id & 31;
    const int b = bh >> 4, h = bh & 15;
    const int t = threadIdx.x;
    const int lane = t & 63;
    const int w = t >> 6;              // wave 0..7
    const int g = lane >> 4;
    const int fr = lane & 15;

    __shared__ __align__(16) short k_lds[2][BKV * NDIM];     // 16 KB
    __shared__ __align__(16) short vt_lds[2][NDIM * VTS];    // 20 KB, V^T [d][kv]
    __shared__ __align__(16) short p_lds[8][32 * PS];        // 20 KB

    const float sc2 = qsc[h] * ksc[h] * (0.08838834764831845f * 1.4426950408889634f); // /sqrt(D)*log2e
    const float vscale = vsc[h];

    const bool heavy = (w < 4);
    const int jq = heavy ? (15 - jj) : jj;
    const int q0 = jq * 128 + (w & 3) * 32;   // this wave's 32 q rows
    const int q_hi = q0 + 31;
    const int nt = (16 - jj) * 4;             // kv tiles of 32 for the heavy tile

    const int* kB = kq + (size_t)b * NSEQ * ROWI + h * NDIM;
    const int* vB = vq + (size_t)b * NSEQ * ROWI + h * NDIM;
    const int* qBp = qq + (size_t)b * NSEQ * ROWI + h * NDIM;

    // ---- Q fragments (exact int->bf16), rows q0 + m*16 + fr ----
    short8 qf[2][4];
    #pragma unroll
    for (int m = 0; m < 2; ++m) {
        const int* qp = qBp + (q0 + m * 16 + fr) * ROWI;
        #pragma unroll
        for (int c = 0; c < 4; ++c) {
            const int d = c * 32 + g * 8;
            int4 a0 = *(const int4*)(qp + d);
            int4 a1 = *(const int4*)(qp + d + 4);
            short8 f;
            f[0]=i2bf(a0.x); f[1]=i2bf(a0.y); f[2]=i2bf(a0.z); f[3]=i2bf(a0.w);
            f[4]=i2bf(a1.x); f[5]=i2bf(a1.y); f[6]=i2bf(a1.z); f[7]=i2bf(a1.w);
            qf[m][c] = f;
        }
    }

    const f32x4 fzero = {0.f, 0.f, 0.f, 0.f};
    f32x4 o_acc[2][8];
    float m_run[2][4], l_run[2][4];
    #pragma unroll
    for (int m = 0; m < 2; ++m) {
        #pragma unroll
        for (int dt = 0; dt < 8; ++dt) o_acc[m][dt] = fzero;
        #pragma unroll
        for (int r = 0; r < 4; ++r) { m_run[m][r] = -1e30f; l_run[m][r] = 0.f; }
    }

    // ---- staging decomposition (512 threads; K 8 ints/thr, V 8 ints/thr) ----
    const int krow = t >> 4;           // 0..31
    const int dk   = (t & 15) * 8;     // 0..120
    const int kv2  = t & 15;           // V: rows 2*kv2, 2*kv2+1
    const int dgv  = t >> 4;           // V: d cols 4*dgv..+3

    int4 ka0, ka1, va0, va1;           // in-flight staging regs (T14)

    auto ISSUE = [&](int tt) {
        const int kv = tt * BKV;
        const int* kp = kB + (kv + krow) * ROWI + dk;
        ka0 = *(const int4*)kp;
        ka1 = *(const int4*)(kp + 4);
        const int* vp = vB + (kv + 2 * kv2) * ROWI + dgv * 4;
        va0 = *(const int4*)vp;
        va1 = *(const int4*)(vp + ROWI);
    };
    auto WRITE = [&](int tt) {
        const int buf = tt & 1;
        short8 kk;
        kk[0]=i2bf(ka0.x); kk[1]=i2bf(ka0.y); kk[2]=i2bf(ka0.z); kk[3]=i2bf(ka0.w);
        kk[4]=i2bf(ka1.x); kk[5]=i2bf(ka1.y); kk[6]=i2bf(ka1.z); kk[7]=i2bf(ka1.w);
        *(short8*)&k_lds[buf][(krow * NDIM + dk) ^ ((krow & 7) << 3)] = kk;
        short* vb = &vt_lds[buf][(dgv * 4) * VTS + kv2 * 2];
        short2v c0 = { i2bf(va0.x), i2bf(va1.x) };
        short2v c1 = { i2bf(va0.y), i2bf(va1.y) };
        short2v c2 = { i2bf(va0.z), i2bf(va1.z) };
        short2v c3 = { i2bf(va0.w), i2bf(va1.w) };
        *(short2v*)(vb + 0 * VTS) = c0;
        *(short2v*)(vb + 1 * VTS) = c1;
        *(short2v*)(vb + 2 * VTS) = c2;
        *(short2v*)(vb + 3 * VTS) = c3;
    };

    ISSUE(0);
    for (int tt = 0; tt < nt; ++tt) {
        WRITE(tt);                       // vmcnt-wait + cvt + ds_write buf[tt&1]
        if (tt + 1 < nt) ISSUE(tt + 1);  // prefetch next tile into regs
        __syncthreads();                 // staged tile visible to all waves

        const int kv0 = tt * BKV;
        if (kv0 > q_hi) continue;        // wave-uniform causal skip
        const int buf = tt & 1;

        // ---- K fragments ----
        short8 kb0[4], kb1[4];
        #pragma unroll
        for (int c = 0; c < 4; ++c) {
            const int d = c * 32 + g * 8;
            const int sw = (fr & 7) << 3;
            kb0[c] = *(const short8*)&k_lds[buf][(fr * NDIM + d) ^ sw];
            kb1[c] = *(const short8*)&k_lds[buf][((16 + fr) * NDIM + d) ^ sw];
        }

        #pragma unroll
        for (int m = 0; m < 2; ++m) {
            f32x4 s0 = fzero, s1 = fzero;
            __builtin_amdgcn_s_setprio(1);
            #pragma unroll
            for (int c = 0; c < 4; ++c) {
                s0 = __builtin_amdgcn_mfma_f32_16x16x32_bf16(qf[m][c], kb0[c], s0, 0, 0, 0);
                s1 = __builtin_amdgcn_mfma_f32_16x16x32_bf16(qf[m][c], kb1[c], s1, 0, 0, 0);
            }
            __builtin_amdgcn_s_setprio(0);

            // C/D layout: col = lane&15 (kv), row = (lane>>4)*4 + r (q)
            const int qrow0 = q0 + m * 16 + g * 4;
            float p0[4], p1[4], rmax[4];
            if (kv0 + BKV - 1 <= q0 + m * 16) {          // fully unmasked (wave-uniform)
                #pragma unroll
                for (int r = 0; r < 4; ++r) {
                    p0[r] = s0[r] * sc2;
                    p1[r] = s1[r] * sc2;
                    rmax[r] = fmaxf(p0[r], p1[r]);
                }
            } else {
                #pragma unroll
                for (int r = 0; r < 4; ++r) {
                    const int qr = qrow0 + r;
                    p0[r] = (kv0 + fr <= qr)      ? s0[r] * sc2 : -1e30f;
                    p1[r] = (kv0 + 16 + fr <= qr) ? s1[r] * sc2 : -1e30f;
                    rmax[r] = fmaxf(p0[r], p1[r]);
                }
            }
            #pragma unroll
            for (int off = 1; off < 16; off <<= 1) {
                #pragma unroll
                for (int r = 0; r < 4; ++r)
                    rmax[r] = fmaxf(rmax[r], __shfl_xor(rmax[r], off, 64));
            }
            bool gr = false;
            #pragma unroll
            for (int r = 0; r < 4; ++r) gr = gr || (rmax[r] > m_run[m][r]);
            if (__any(gr ? 1 : 0)) {                      // rescale only when max grows (exact)
                float sf[4];
                #pragma unroll
                for (int r = 0; r < 4; ++r) {
                    const float mn = fmaxf(m_run[m][r], rmax[r]);
                    sf[r] = exp2f(m_run[m][r] - mn);
                    m_run[m][r] = mn;
                    l_run[m][r] *= sf[r];
                }
                #pragma unroll
                for (int dt = 0; dt < 8; ++dt) {
                    #pragma unroll
                    for (int r = 0; r < 4; ++r) o_acc[m][dt][r] *= sf[r];
                }
            }
            float psum[4];
            #pragma unroll
            for (int r = 0; r < 4; ++r) {
                p0[r] = exp2f(p0[r] - m_run[m][r]);
                p1[r] = exp2f(p1[r] - m_run[m][r]);
                psum[r] = p0[r] + p1[r];
            }
            #pragma unroll
            for (int off = 1; off < 16; off <<= 1) {
                #pragma unroll
                for (int r = 0; r < 4; ++r)
                    psum[r] += __shfl_xor(psum[r], off, 64);
            }
            #pragma unroll
            for (int r = 0; r < 4; ++r) l_run[m][r] += psum[r];
            #pragma unroll
            for (int r = 0; r < 4; ++r) {
                const int qr = m * 16 + g * 4 + r;
                p_lds[w][qr * PS + fr]      = f2bf(p0[r]);
                p_lds[w][qr * PS + 16 + fr] = f2bf(p1[r]);
            }
        }

        // ---- PV ----
        short8 pa0 = *(const short8*)&p_lds[w][(0 * 16 + fr) * PS + g * 8];
        short8 pa1 = *(const short8*)&p_lds[w][(1 * 16 + fr) * PS + g * 8];
        __builtin_amdgcn_s_setprio(1);
        #pragma unroll
        for (int dt = 0; dt < 8; ++dt) {
            short8 vb = *(const short8*)&vt_lds[buf][(dt * 16 + fr) * VTS + g * 8];
            o_acc[0][dt] = __builtin_amdgcn_mfma_f32_16x16x32_bf16(pa0, vb, o_acc[0][dt], 0, 0, 0);
            o_acc[1][dt] = __builtin_amdgcn_mfma_f32_16x16x32_bf16(pa1, vb, o_acc[1][dt], 0, 0, 0);
        }
        __builtin_amdgcn_s_setprio(0);
    }

    // ---- epilogue ----
    #pragma unroll
    for (int m = 0; m < 2; ++m) {
        #pragma unroll
        for (int r = 0; r < 4; ++r) {
            const int qrow = q0 + m * 16 + g * 4 + r;
            const float scale_r = vscale / l_run[m][r];
            float* op = out + (size_t)(b * NSEQ + qrow) * ROWI + h * NDIM;
            #pragma unroll
            for (int dt = 0; dt < 8; ++dt)
                op[dt * 16 + fr] = o_acc[m][dt][r] * scale_r;
        }
    }
}

extern "C" void kernel_launch(void* const* d_in, const int* in_sizes, int n_in,
                              void* d_out, int out_size, void* d_ws, size_t ws_size,
                              hipStream_t stream) {
    const int* qq = (const int*)d_in[0];
    const int* kq = (const int*)d_in[1];
    const int* vq = (const int*)d_in[2];
    const float* qsc = (const float*)d_in[3];
    const float* ksc = (const float*)d_in[4];
    const float* vsc = (const float*)d_in[5];
    float* out = (float*)d_out;
    (void)d_ws; (void)ws_size; (void)in_sizes; (void)n_in; (void)out_size;

    qattn_fwd<<<dim3(256), dim3(512), 0, stream>>>(qq, kq, vq, qsc, ksc, vsc, out);
}

// Round 3
// 106.718 us; speedup vs baseline: 2.2705x; 1.4570x over previous
//
#include <hip/hip_runtime.h>
#include <hip/hip_bf16.h>

typedef __attribute__((ext_vector_type(8))) short short8;
typedef __attribute__((ext_vector_type(4))) short short4v;
typedef __attribute__((ext_vector_type(2))) short short2v;
typedef __attribute__((ext_vector_type(4))) float f32x4;

namespace {
constexpr int NSEQ = 2048;
constexpr int NHEAD = 16;
constexpr int NDIM = 128;
constexpr int BKV = 32;
constexpr int VTS = 40;              // vt_lds row stride (shorts)
constexpr int ROWI = NHEAD * NDIM;   // 2048 ints per seq row
}

// int in [-128,127] -> bf16 bits, exact
__device__ __forceinline__ short i2bf(int v) {
    union { float f; unsigned u; } x; x.f = (float)v;
    return (short)(x.u >> 16);
}
// float -> bf16 bits, RNE
__device__ __forceinline__ short f2bf(float f) {
    union { float f; unsigned u; } x; x.f = f;
    unsigned u = (x.u + 0x7fffu + ((x.u >> 16) & 1u)) >> 16;
    return (short)u;
}

__global__ __launch_bounds__(512, 2)
void qattn_fwd(const int* __restrict__ qq, const int* __restrict__ kq,
               const int* __restrict__ vq, const float* __restrict__ qsc,
               const float* __restrict__ ksc, const float* __restrict__ vsc,
               float* __restrict__ out)
{
    const int id = blockIdx.x;
    const int jj = id >> 5;            // pair index 0..7
    const int bh = id & 31;
    const int b = bh >> 4, h = bh & 15;
    const int t = threadIdx.x;
    const int lane = t & 63;
    const int w = t >> 6;              // wave 0..7
    const int g = lane >> 4;           // 0..3
    const int fr = lane & 15;

    __shared__ __align__(16) short k_lds[2][BKV * NDIM];     // 16 KB
    __shared__ __align__(16) short vt_lds[2][NDIM * VTS];    // 20 KB, V^T [d][kv]
    __shared__ __align__(16) short pq[8][2][4 * 16 * 8];     // 16 KB, P^T [gp][fr][e]

    const float sc2 = qsc[h] * ksc[h] * (0.08838834764831845f * 1.4426950408889634f);
    const float vscale = vsc[h];

    const bool heavy = (w < 4);
    const int jq = heavy ? (15 - jj) : jj;
    const int q0 = jq * 128 + (w & 3) * 32;   // this wave's 32 q rows
    const int q_hi = q0 + 31;
    const int nt = (16 - jj) * 4;             // kv tiles staged (covers both q-tiles)

    const int* kB = kq + (size_t)b * NSEQ * ROWI + h * NDIM;
    const int* vB = vq + (size_t)b * NSEQ * ROWI + h * NDIM;
    const int* qBp = qq + (size_t)b * NSEQ * ROWI + h * NDIM;

    // ---- Q fragments (exact int->bf16), rows q0 + m*16 + fr ----
    short8 qf[2][4];
    #pragma unroll
    for (int m = 0; m < 2; ++m) {
        const int* qp = qBp + (q0 + m * 16 + fr) * ROWI;
        #pragma unroll
        for (int c = 0; c < 4; ++c) {
            const int d = c * 32 + g * 8;
            int4 a0 = *(const int4*)(qp + d);
            int4 a1 = *(const int4*)(qp + d + 4);
            short8 f;
            f[0]=i2bf(a0.x); f[1]=i2bf(a0.y); f[2]=i2bf(a0.z); f[3]=i2bf(a0.w);
            f[4]=i2bf(a1.x); f[5]=i2bf(a1.y); f[6]=i2bf(a1.z); f[7]=i2bf(a1.w);
            qf[m][c] = f;
        }
    }

    const f32x4 fzero = {0.f, 0.f, 0.f, 0.f};
    f32x4 o_acc[2][8];                 // O^T: o_acc[m][dt][r] = O[d=dt*16+g*4+r][q=q0+m*16+fr]
    float m_run[2], l_run[2];          // per-lane scalars (lane owns q row fr per m)
    #pragma unroll
    for (int m = 0; m < 2; ++m) {
        #pragma unroll
        for (int dt = 0; dt < 8; ++dt) o_acc[m][dt] = fzero;
        m_run[m] = -1e30f; l_run[m] = 0.f;
    }

    // ---- staging decomposition (512 threads) ----
    const int krow = t >> 4;           // 0..31
    const int dk   = (t & 15) * 8;     // 0..120
    const int kv2  = t & 15;           // V: rows 2*kv2, 2*kv2+1
    const int dgv  = t >> 4;           // V: d cols 4*dgv..+3

    int4 ka0, ka1, va0, va1;

    auto ISSUE = [&](int tt) {
        const int kv = tt * BKV;
        const int* kp = kB + (kv + krow) * ROWI + dk;
        ka0 = *(const int4*)kp;
        ka1 = *(const int4*)(kp + 4);
        const int* vp = vB + (kv + 2 * kv2) * ROWI + dgv * 4;
        va0 = *(const int4*)vp;
        va1 = *(const int4*)(vp + ROWI);
    };
    auto WRITE = [&](int tt) {
        const int buf = tt & 1;
        short8 kk;
        kk[0]=i2bf(ka0.x); kk[1]=i2bf(ka0.y); kk[2]=i2bf(ka0.z); kk[3]=i2bf(ka0.w);
        kk[4]=i2bf(ka1.x); kk[5]=i2bf(ka1.y); kk[6]=i2bf(ka1.z); kk[7]=i2bf(ka1.w);
        *(short8*)&k_lds[buf][(krow * NDIM + dk) ^ ((krow & 7) << 3)] = kk;
        short* vb = &vt_lds[buf][(dgv * 4) * VTS + kv2 * 2];
        short2v c0 = { i2bf(va0.x), i2bf(va1.x) };
        short2v c1 = { i2bf(va0.y), i2bf(va1.y) };
        short2v c2 = { i2bf(va0.z), i2bf(va1.z) };
        short2v c3 = { i2bf(va0.w), i2bf(va1.w) };
        *(short2v*)(vb + 0 * VTS) = c0;
        *(short2v*)(vb + 1 * VTS) = c1;
        *(short2v*)(vb + 2 * VTS) = c2;
        *(short2v*)(vb + 3 * VTS) = c3;
    };

    ISSUE(0);
    for (int tt = 0; tt < nt; ++tt) {
        WRITE(tt);
        if (tt + 1 < nt) ISSUE(tt + 1);
        __syncthreads();

        const int kv0 = tt * BKV;
        if (kv0 > q_hi) continue;        // wave-uniform causal skip
        const int buf = tt & 1;

        // ---- K fragments (A-operand: [16 kv][32 d-chunk]) ----
        short8 kb0[4], kb1[4];
        #pragma unroll
        for (int c = 0; c < 4; ++c) {
            const int d = c * 32 + g * 8;
            const int sw = (fr & 7) << 3;
            kb0[c] = *(const short8*)&k_lds[buf][(fr * NDIM + d) ^ sw];
            kb1[c] = *(const short8*)&k_lds[buf][((16 + fr) * NDIM + d) ^ sw];
        }

        // ---- swapped QK^T + in-register softmax ----
        #pragma unroll
        for (int m = 0; m < 2; ++m) {
            f32x4 s0 = fzero, s1 = fzero;
            __builtin_amdgcn_s_setprio(1);
            #pragma unroll
            for (int c = 0; c < 4; ++c) {
                s0 = __builtin_amdgcn_mfma_f32_16x16x32_bf16(kb0[c], qf[m][c], s0, 0, 0, 0);
                s1 = __builtin_amdgcn_mfma_f32_16x16x32_bf16(kb1[c], qf[m][c], s1, 0, 0, 0);
            }
            __builtin_amdgcn_s_setprio(0);
            // C = S^T: col = fr = q (q0+m*16+fr), row = g*4+r = kv-within-16
            const int qr = q0 + m * 16 + fr;
            const int g4 = g * 4;
            float p8[8];
            if (kv0 + BKV - 1 <= q0 + m * 16) {          // fully unmasked (wave-uniform)
                #pragma unroll
                for (int r = 0; r < 4; ++r) {
                    p8[r]     = s0[r] * sc2;
                    p8[4 + r] = s1[r] * sc2;
                }
            } else {
                #pragma unroll
                for (int r = 0; r < 4; ++r) {
                    p8[r]     = (kv0 + g4 + r <= qr)      ? s0[r] * sc2 : -1e30f;
                    p8[4 + r] = (kv0 + 16 + g4 + r <= qr) ? s1[r] * sc2 : -1e30f;
                }
            }
            float rmax = fmaxf(fmaxf(fmaxf(p8[0], p8[1]), fmaxf(p8[2], p8[3])),
                               fmaxf(fmaxf(p8[4], p8[5]), fmaxf(p8[6], p8[7])));
            rmax = fmaxf(rmax, __shfl_xor(rmax, 16, 64));
            rmax = fmaxf(rmax, __shfl_xor(rmax, 32, 64));
            if (__any((rmax > m_run[m]) ? 1 : 0)) {      // rescale only when max grows
                const float mn = fmaxf(m_run[m], rmax);
                const float sf = exp2f(m_run[m] - mn);
                m_run[m] = mn;
                l_run[m] *= sf;
                #pragma unroll
                for (int dt = 0; dt < 8; ++dt) {
                    #pragma unroll
                    for (int r = 0; r < 4; ++r) o_acc[m][dt][r] *= sf;
                }
            }
            float psum = 0.f;
            #pragma unroll
            for (int j = 0; j < 8; ++j) {
                p8[j] = exp2f(p8[j] - m_run[m]);
                psum += p8[j];
            }
            psum += __shfl_xor(psum, 16, 64);
            psum += __shfl_xor(psum, 32, 64);
            l_run[m] += psum;
            // write P^T quads: pq[w][m][gp*128 + fr*8 + e], e = 4*(g&1)+r, gp = g>>1 (+2 for s1)
            short4v lo = { f2bf(p8[0]), f2bf(p8[1]), f2bf(p8[2]), f2bf(p8[3]) };
            short4v hi = { f2bf(p8[4]), f2bf(p8[5]), f2bf(p8[6]), f2bf(p8[7]) };
            short* base = &pq[w][m][0];
            *(short4v*)(base + (g >> 1) * 128 + fr * 8 + (g & 1) * 4) = lo;
            *(short4v*)(base + (2 + (g >> 1)) * 128 + fr * 8 + (g & 1) * 4) = hi;
        }

        // ---- swapped PV: O^T[d][q] += V^T[d][kv] * P^T[kv][q] ----
        short8 pb0 = *(const short8*)&pq[w][0][g * 128 + fr * 8];
        short8 pb1 = *(const short8*)&pq[w][1][g * 128 + fr * 8];
        __builtin_amdgcn_s_setprio(1);
        #pragma unroll
        for (int dt = 0; dt < 8; ++dt) {
            short8 vb = *(const short8*)&vt_lds[buf][(dt * 16 + fr) * VTS + g * 8];
            o_acc[0][dt] = __builtin_amdgcn_mfma_f32_16x16x32_bf16(vb, pb0, o_acc[0][dt], 0, 0, 0);
            o_acc[1][dt] = __builtin_amdgcn_mfma_f32_16x16x32_bf16(vb, pb1, o_acc[1][dt], 0, 0, 0);
        }
        __builtin_amdgcn_s_setprio(0);
    }

    // ---- epilogue: O^T -> out, per-lane scalar normalize ----
    #pragma unroll
    for (int m = 0; m < 2; ++m) {
        const int qrow = q0 + m * 16 + fr;
        const float sr = vscale / l_run[m];
        float* op = out + (size_t)(b * NSEQ + qrow) * ROWI + h * NDIM;
        #pragma unroll
        for (int dt = 0; dt < 8; ++dt) {
            f32x4 v = o_acc[m][dt];
            v[0] *= sr; v[1] *= sr; v[2] *= sr; v[3] *= sr;
            *(f32x4*)(op + dt * 16 + g * 4) = v;
        }
    }
}

extern "C" void kernel_launch(void* const* d_in, const int* in_sizes, int n_in,
                              void* d_out, int out_size, void* d_ws, size_t ws_size,
                              hipStream_t stream) {
    const int* qq = (const int*)d_in[0];
    const int* kq = (const int*)d_in[1];
    const int* vq = (const int*)d_in[2];
    const float* qsc = (const float*)d_in[3];
    const float* ksc = (const float*)d_in[4];
    const float* vsc = (const float*)d_in[5];
    float* out = (float*)d_out;
    (void)d_ws; (void)ws_size; (void)in_sizes; (void)n_in; (void)out_size;

    qattn_fwd<<<dim3(256), dim3(512), 0, stream>>>(qq, kq, vq, qsc, ksc, vsc, out);
}